// Round 9
// baseline (344.172 us; speedup 1.0000x reference)
//
#include <hip/hip_runtime.h>
#include <stdint.h>
#include <math.h>

// Problem constants (DBRX FFN): B=2 S=2048 D=1024 E=8 F=2048 K=2
#define NB 2
#define NS 2048
#define ND 1024
#define NE 8
#define NF 2048
#define NTOK (NB*NS)          // 4096 tokens
#define EFD ((size_t)NE*NF*ND)

typedef short bf16x8 __attribute__((ext_vector_type(8)));
typedef float f32x4 __attribute__((ext_vector_type(4)));

__device__ __forceinline__ unsigned short f2bf(float f) {
  unsigned u = __float_as_uint(f);
  unsigned r = (u + 0x7FFFu + ((u >> 16) & 1u)) >> 16;
  return (unsigned short)r;
}

__device__ __forceinline__ void async16(unsigned short* lds, const unsigned short* g) {
  __builtin_amdgcn_global_load_lds(
      (const __attribute__((address_space(1))) unsigned int*)g,
      (__attribute__((address_space(3))) unsigned int*)lds, 16, 0, 0);
}

#define VMCNT(n) asm volatile("s_waitcnt vmcnt(" #n ")" ::: "memory")
#define LGKM0    asm volatile("s_waitcnt lgkmcnt(0)" ::: "memory")
#define SBAR     __builtin_amdgcn_s_barrier()
#define SCHED0   __builtin_amdgcn_sched_barrier(0)

// ---------------- convert fp32 -> bf16 (vectorized) ----------------
__global__ void cvt_bf16(const float* __restrict__ src,
                         unsigned short* __restrict__ dst, int n4) {
  int i = blockIdx.x * blockDim.x + threadIdx.x;
  int stride = gridDim.x * blockDim.x;
  for (; i < n4; i += stride) {
    float4 v = ((const float4*)src)[i];
    ushort4 o;
    o.x = f2bf(v.x); o.y = f2bf(v.y); o.z = f2bf(v.z); o.w = f2bf(v.w);
    ((ushort4*)dst)[i] = o;
  }
}

// ---------------- transpose w2 (E,F,D) fp32 -> w2t (E,D,F) bf16 ----------------
__global__ void transpose_w2(const float* __restrict__ w2,
                             unsigned short* __restrict__ w2t) {
  __shared__ float tile[32][33];
  int e = blockIdx.z;
  int d0 = blockIdx.x * 32, f0 = blockIdx.y * 32;
  int tx = threadIdx.x, ty = threadIdx.y;
  const float* src = w2 + (size_t)e * NF * ND;
  unsigned short* dst = w2t + (size_t)e * ND * NF;
#pragma unroll
  for (int i = ty; i < 32; i += 8)
    tile[i][tx] = src[(size_t)(f0 + i) * ND + d0 + tx];
  __syncthreads();
#pragma unroll
  for (int i = ty; i < 32; i += 8)
    dst[(size_t)(d0 + i) * NF + f0 + tx] = f2bf(tile[tx][i]);
}

// ---------------- router: wave per 16 tokens, 4 lanes per token ----------------
__global__ void router_kernel(const float* __restrict__ hs,
                              const float* __restrict__ rk,
                              float* __restrict__ wout,   // [NTOK][NE]
                              float* __restrict__ tw,     // [NTOK][2]
                              int* __restrict__ choice,   // [NTOK] e0 | e1<<4
                              unsigned short* __restrict__ hsb) {
  int lane = threadIdx.x;            // 64
  int tt = lane & 15, part = lane >> 4;
  int t = blockIdx.x * 16 + tt;      // 256 blocks
  const float4* hrow = (const float4*)(hs + (size_t)t * ND) + part * 64;
  ushort4* hb4 = (ushort4*)(hsb + (size_t)t * ND) + part * 64;
  const float4* rk4 = (const float4*)rk + part * 512;
  float acc[NE];
#pragma unroll
  for (int e = 0; e < NE; ++e) acc[e] = 0.f;
#pragma unroll 4
  for (int i = 0; i < 64; ++i) {
    float4 x = hrow[i];
    ushort4 o;
    o.x = f2bf(x.x); o.y = f2bf(x.y); o.z = f2bf(x.z); o.w = f2bf(x.w);
    hb4[i] = o;
    float xs[4] = {x.x, x.y, x.z, x.w};
#pragma unroll
    for (int j = 0; j < 4; ++j) {
      float4 r0 = rk4[i * 8 + j * 2];
      float4 r1 = rk4[i * 8 + j * 2 + 1];
      acc[0] += xs[j] * r0.x; acc[1] += xs[j] * r0.y;
      acc[2] += xs[j] * r0.z; acc[3] += xs[j] * r0.w;
      acc[4] += xs[j] * r1.x; acc[5] += xs[j] * r1.y;
      acc[6] += xs[j] * r1.z; acc[7] += xs[j] * r1.w;
    }
  }
#pragma unroll
  for (int e = 0; e < NE; ++e) {
    acc[e] += __shfl_xor(acc[e], 16, 64);
    acc[e] += __shfl_xor(acc[e], 32, 64);
  }
  if (part == 0) {
    float mx = acc[0]; int i0 = 0;
#pragma unroll
    for (int e = 1; e < NE; ++e) if (acc[e] > mx) { mx = acc[e]; i0 = e; }
    float m2 = -3.4e38f; int i1 = 0;
#pragma unroll
    for (int e = 0; e < NE; ++e) if (e != i0 && acc[e] > m2) { m2 = acc[e]; i1 = e; }
    float p[NE]; float den = 0.f;
#pragma unroll
    for (int e = 0; e < NE; ++e) { p[e] = expf(acc[e] - mx); den += p[e]; }
    float inv = 1.f / den;
#pragma unroll
    for (int e = 0; e < NE; ++e) { p[e] *= inv; wout[t * NE + e] = p[e]; }
    float w0 = p[i0], w1 = p[i1];
    float s = 1.f / (w0 + w1);
    tw[t * 2 + 0] = w0 * s;
    tw[t * 2 + 1] = w1 * s;
    choice[t] = i0 | (i1 << 4);
  }
}

// ---------------- build per-expert token lists (single block, LDS atomics) ----
__global__ void build_lists(const int* __restrict__ choice,
                            int* __restrict__ counts,
                            int* __restrict__ list) {
  __shared__ int lcnt[NE];
  int tid = threadIdx.x;  // 1024
  if (tid < NE) lcnt[tid] = 0;
  __syncthreads();
  int4 c4 = ((const int4*)choice)[tid];
  int cs[4] = {c4.x, c4.y, c4.z, c4.w};
#pragma unroll
  for (int j = 0; j < 4; ++j) {
    int t = tid * 4 + j;
    int e0 = cs[j] & 15, e1 = (cs[j] >> 4) & 15;
    int p0 = atomicAdd(&lcnt[e0], 1);
    list[e0 * NTOK + p0] = t << 1;
    int p1 = atomicAdd(&lcnt[e1], 1);
    list[e1 * NTOK + p1] = (t << 1) | 1;
  }
  __syncthreads();
  if (tid < NE) counts[tid] = lcnt[tid];
}

// ============ fused pass1+2: BM=256, 8 waves, wave-group split ===============
// 512 thr = 8 waves. g = wid>>2: 0 -> x1 (w1), 1 -> x2 (v1).
// Within group: wm=(wid>>1)&1 (128-row half), wc=wid&1 (64-col half).
// BM=256 gathered token rows, BN=128 per matrix, BK=32.
// Ring-3 32KB bufs (96KB LDS, 1 block/CU), stage-ahead-2, VMCNT(8/4/0)
// (4 loads/thread/buf), chunk-XOR swizzle slot^((row>>1)&3) (0-conflict).
// Epilogue: 2 rounds of LDS fp32 exchange [256][66]; x1 waves apply silu -> H.
__global__ __launch_bounds__(512, 2) void gemm_fused(
    const int* __restrict__ counts, const int* __restrict__ list,
    const unsigned short* __restrict__ A,    // hsb [NTOK][ND]
    const unsigned short* __restrict__ B1,   // w1b [E][F][D]
    const unsigned short* __restrict__ B2,   // v1b
    unsigned short* __restrict__ H) {        // hbuf [2*NTOK][NF]
  int bid = blockIdx.x;
  int e = bid >> 8;                  // 8e x 16mt x 16nt = 2048
  int rem = bid & 255;
  int mt = rem >> 4, nt = rem & 15;  // nt fastest
  int cnt = counts[e];
  if (mt * 256 >= cnt) return;

  __shared__ char smem[98304];       // ring-3 x 32KB; epilogue xl 256x66 fp32

  int tid = threadIdx.x;
  int wid = tid >> 6, lane = tid & 63;
  int g = wid >> 2;                  // matrix group
  int wm = (wid >> 1) & 1, wc = wid & 1;
  int l15 = lane & 15, l4 = lane >> 4;
  const int* mylist = list + e * NTOK;

  // staging: 4 async16/thread: A-lo, A-hi, B1, B2
  int trow = tid >> 2;                          // 0..127
  int co = ((tid & 3) ^ ((tid >> 3) & 3)) * 8;  // inverse-swizzled elem offset
  const unsigned short* aS[2];
#pragma unroll
  for (int h = 0; h < 2; ++h) {
    int r = mt * 256 + h * 128 + trow;
    if (r >= cnt) r = cnt - 1;
    int entry = mylist[r];
    aS[h] = A + (size_t)(entry >> 1) * ND + co;
  }
  const unsigned short* b1S =
      B1 + (size_t)e * NF * ND + (size_t)(nt * 128 + trow) * ND + co;
  const unsigned short* b2S =
      B2 + (size_t)e * NF * ND + (size_t)(nt * 128 + trow) * ND + co;

  // swizzled fragment read byte offsets (A region 16KB, B1 @16384, B2 @24576)
  int offA[8], offB[4];
#pragma unroll
  for (int mi = 0; mi < 8; ++mi) {
    int r = wm * 128 + mi * 16 + l15;
    offA[mi] = r * 64 + ((l4 ^ ((r >> 1) & 3)) << 4);
  }
#pragma unroll
  for (int ni = 0; ni < 4; ++ni) {
    int r = wc * 64 + ni * 16 + l15;
    offB[ni] = 16384 + g * 8192 + r * 64 + ((l4 ^ ((r >> 1) & 3)) << 4);
  }

  f32x4 acc[8][4];
#pragma unroll
  for (int mi = 0; mi < 8; ++mi)
#pragma unroll
    for (int ni = 0; ni < 4; ++ni) {
      f32x4 z = {0.f, 0.f, 0.f, 0.f};
      acc[mi][ni] = z;
    }

  auto STAGE = [&](int c, int kt) {
    int ko = kt * 32;
    unsigned short* base = (unsigned short*)(smem + c * 32768) + tid * 8;
    async16(base,         aS[0] + ko);
    async16(base + 4096,  aS[1] + ko);
    async16(base + 8192,  b1S + ko);
    async16(base + 12288, b2S + ko);
  };

  const int kT = ND / 32;  // 32
  STAGE(0, 0); STAGE(1, 1); STAGE(2, 2);

  int cur = 0;
  for (int kt = 0; kt < kT; ++kt) {
    if (kt + 2 < kT)      { VMCNT(8); }
    else if (kt + 1 < kT) { VMCNT(4); }
    else                  { VMCNT(0); }
    SCHED0;
    SBAR;                               // buf[cur] landed for all waves

    const char* buf = smem + cur * 32768;
    bf16x8 a[8], b[4];
#pragma unroll
    for (int mi = 0; mi < 8; ++mi)
      a[mi] = *(const bf16x8*)(buf + offA[mi]);
#pragma unroll
    for (int ni = 0; ni < 4; ++ni)
      b[ni] = *(const bf16x8*)(buf + offB[ni]);
    LGKM0;
    SCHED0;
    SBAR;                               // all waves' reads of buf[cur] done
    if (kt + 3 < kT) STAGE(cur, kt + 3);

    __builtin_amdgcn_s_setprio(1);
#pragma unroll
    for (int mi = 0; mi < 8; ++mi)
#pragma unroll
      for (int ni = 0; ni < 4; ++ni)
        acc[mi][ni] = __builtin_amdgcn_mfma_f32_16x16x32_bf16(
            a[mi], b[ni], acc[mi][ni], 0, 0, 0);
    __builtin_amdgcn_s_setprio(0);

    cur = (cur == 2) ? 0 : cur + 1;
  }

  // ---- epilogue: 2 rounds of x2->LDS exchange, x1 waves emit H ----
  __syncthreads();                      // loop reads done; staging drained
  float* xl = (float*)smem;             // [256][66] fp32 = 67.6KB
#pragma unroll
  for (int r2 = 0; r2 < 2; ++r2) {
    if (g == 1 && wc == r2) {
#pragma unroll
      for (int mi = 0; mi < 8; ++mi)
#pragma unroll
        for (int j = 0; j < 4; ++j) {
          int row = wm * 128 + mi * 16 + l4 * 4 + j;
#pragma unroll
          for (int ni = 0; ni < 4; ++ni)
            xl[row * 66 + ni * 16 + l15] = acc[mi][ni][j];
        }
    }
    __syncthreads();
    if (g == 0 && wc == r2) {
      int f0 = nt * 128 + r2 * 64;
#pragma unroll
      for (int mi = 0; mi < 8; ++mi)
#pragma unroll
        for (int j = 0; j < 4; ++j) {
          int row = wm * 128 + mi * 16 + l4 * 4 + j;
          int r = mt * 256 + row;
          if (r >= cnt) continue;
          int entry = mylist[r];
          long crow = (long)(entry & 1) * NTOK + (entry >> 1);
#pragma unroll
          for (int ni = 0; ni < 4; ++ni) {
            int col = ni * 16 + l15;
            float x1 = acc[mi][ni][j];
            float x2 = xl[row * 66 + col];
            float h = (x1 / (1.f + expf(-x1))) * x2;
            H[crow * (long)NF + f0 + col] = f2bf(h);
          }
        }
    }
    __syncthreads();
  }
}

// ============ pass3: y = h @ w2t^T, BM=256, BN=256, split-K=2 ================
// 512 thr = 8 waves (2M x 4N): wm=wid>>2, wn=wid&3; wave tile 128x64.
// Ring-3 32KB bufs (96KB LDS), VMCNT(8/4/0), same swizzle.
__global__ __launch_bounds__(512, 2) void gemm_p3(
    const int* __restrict__ counts, const int* __restrict__ list,
    const unsigned short* __restrict__ Ah,   // hbuf [2*NTOK][NF]
    const unsigned short* __restrict__ Bw,   // w2t [E][ND][NF]
    float* __restrict__ Y) {                 // [2 kh][2*NTOK][ND] fp32
  int bid = blockIdx.x;
  int e = bid >> 7;                   // 8e x 16mt x 4nt x 2kh = 1024
  int rem = bid & 127;
  int mt = rem >> 3;
  int code = rem & 7;
  int nt = code >> 1, kh = code & 1;
  int cnt = counts[e];
  if (mt * 256 >= cnt) return;

  __shared__ char smem[98304];        // ring-3 x 32KB (A 16KB + B 16KB)

  int tid = threadIdx.x;
  int wid = tid >> 6, lane = tid & 63;
  int wm = wid >> 2, wn = wid & 3;
  int l15 = lane & 15, l4 = lane >> 4;
  const int* mylist = list + e * NTOK;

  int trow = tid >> 2;                          // 0..127
  int co = ((tid & 3) ^ ((tid >> 3) & 3)) * 8;
  const unsigned short* aS[2];
#pragma unroll
  for (int h = 0; h < 2; ++h) {
    int r = mt * 256 + h * 128 + trow;
    if (r >= cnt) r = cnt - 1;
    int entry = mylist[r];
    long crow = (long)(entry & 1) * NTOK + (entry >> 1);
    aS[h] = Ah + crow * (long)NF + kh * 1024 + co;
  }
  const unsigned short* bS[2];
#pragma unroll
  for (int h = 0; h < 2; ++h) {
    int d = nt * 256 + h * 128 + trow;
    bS[h] = Bw + (size_t)e * ND * NF + (size_t)d * NF + kh * 1024 + co;
  }

  int offA[8], offB[4];
#pragma unroll
  for (int mi = 0; mi < 8; ++mi) {
    int r = wm * 128 + mi * 16 + l15;
    offA[mi] = r * 64 + ((l4 ^ ((r >> 1) & 3)) << 4);
  }
#pragma unroll
  for (int ni = 0; ni < 4; ++ni) {
    int r = wn * 64 + ni * 16 + l15;
    offB[ni] = 16384 + r * 64 + ((l4 ^ ((r >> 1) & 3)) << 4);
  }

  f32x4 acc[8][4];
#pragma unroll
  for (int mi = 0; mi < 8; ++mi)
#pragma unroll
    for (int ni = 0; ni < 4; ++ni) {
      f32x4 z = {0.f, 0.f, 0.f, 0.f};
      acc[mi][ni] = z;
    }

  auto STAGE = [&](int c, int kt) {
    int ko = kt * 32;
    unsigned short* base = (unsigned short*)(smem + c * 32768) + tid * 8;
    async16(base,         aS[0] + ko);
    async16(base + 4096,  aS[1] + ko);
    async16(base + 8192,  bS[0] + ko);
    async16(base + 12288, bS[1] + ko);
  };

  const int kT = 32;   // 1024 (per kh) / 32
  STAGE(0, 0); STAGE(1, 1); STAGE(2, 2);

  int cur = 0;
  for (int kt = 0; kt < kT; ++kt) {
    if (kt + 2 < kT)      { VMCNT(8); }
    else if (kt + 1 < kT) { VMCNT(4); }
    else                  { VMCNT(0); }
    SCHED0;
    SBAR;

    const char* buf = smem + cur * 32768;
    bf16x8 a[8], b[4];
#pragma unroll
    for (int mi = 0; mi < 8; ++mi)
      a[mi] = *(const bf16x8*)(buf + offA[mi]);
#pragma unroll
    for (int ni = 0; ni < 4; ++ni)
      b[ni] = *(const bf16x8*)(buf + offB[ni]);
    LGKM0;
    SCHED0;
    SBAR;
    if (kt + 3 < kT) STAGE(cur, kt + 3);

    __builtin_amdgcn_s_setprio(1);
#pragma unroll
    for (int mi = 0; mi < 8; ++mi)
#pragma unroll
      for (int ni = 0; ni < 4; ++ni)
        acc[mi][ni] = __builtin_amdgcn_mfma_f32_16x16x32_bf16(
            a[mi], b[ni], acc[mi][ni], 0, 0, 0);
    __builtin_amdgcn_s_setprio(0);

    cur = (cur == 2) ? 0 : cur + 1;
  }

  float* Yp = Y + (size_t)kh * 2 * NTOK * ND;
#pragma unroll
  for (int mi = 0; mi < 8; ++mi)
#pragma unroll
    for (int j = 0; j < 4; ++j) {
      int r = mt * 256 + wm * 128 + mi * 16 + l4 * 4 + j;
      if (r >= cnt) continue;
      int entry = mylist[r];
      long crow = (long)(entry & 1) * NTOK + (entry >> 1);
#pragma unroll
      for (int ni = 0; ni < 4; ++ni) {
        int d = nt * 256 + wn * 64 + ni * 16 + l15;
        Yp[crow * (long)ND + d] = acc[mi][ni][j];
      }
    }
}

// ---------------- combine: out = tw0*(y0a+y0b) + tw1*(y1a+y1b) --------------
__global__ void combine_kernel(const float* __restrict__ ybuf,
                               const float* __restrict__ tw,
                               float* __restrict__ out) {
  const int S4 = NTOK * ND / 4;        // slot stride (float4)
  const int KH4 = 2 * NTOK * ND / 4;   // kh stride (float4)
  int i = blockIdx.x * blockDim.x + threadIdx.x;
  int stride = gridDim.x * blockDim.x;
  const float4* yb = (const float4*)ybuf;
  for (; i < S4; i += stride) {
    int t = i >> 8;
    float w0 = tw[t * 2], w1 = tw[t * 2 + 1];
    float4 a0 = yb[i], b0 = yb[i + KH4];
    float4 a1 = yb[i + S4], b1 = yb[i + S4 + KH4];
    float4 o;
    o.x = w0 * (a0.x + b0.x) + w1 * (a1.x + b1.x);
    o.y = w0 * (a0.y + b0.y) + w1 * (a1.y + b1.y);
    o.z = w0 * (a0.z + b0.z) + w1 * (a1.z + b1.z);
    o.w = w0 * (a0.w + b0.w) + w1 * (a1.w + b1.w);
    ((float4*)out)[i] = o;
  }
}

// ---------------- workspace layout (bytes) ----------------
// counts:   0         (256)
// list:     256       (131072)     end 131328
// tw:       131328    (32768)      end 164096
// choice:   164096    (16384)      end 180480
// hsb:      180480    (8388608)    end 8569088
// w1b:      8569088   (33554432)   end 42123520
// v1b:      42123520  (33554432)   end 75677952
// w2t:      75677952  (33554432)   end 109232384
// hbuf:     109232384 (33554432)   end 142786816
// ybuf:     142786816 (67108864)   end 209895680   [2 kh][2*NTOK][ND] fp32

extern "C" void kernel_launch(void* const* d_in, const int* in_sizes, int n_in,
                              void* d_out, int out_size, void* d_ws, size_t ws_size,
                              hipStream_t stream) {
  const float* hs = (const float*)d_in[0];
  const float* rk = (const float*)d_in[1];
  const float* w1 = (const float*)d_in[2];
  const float* v1 = (const float*)d_in[3];
  const float* w2 = (const float*)d_in[4];
  float* out = (float*)d_out;
  float* wout = out + (size_t)NTOK * ND;

  char* ws = (char*)d_ws;
  int* counts = (int*)(ws + 0);
  int* list = (int*)(ws + 256);
  float* tw = (float*)(ws + 131328);
  int* choice = (int*)(ws + 164096);
  unsigned short* hsb = (unsigned short*)(ws + 180480);
  unsigned short* w1b = (unsigned short*)(ws + 8569088);
  unsigned short* v1b = (unsigned short*)(ws + 42123520);
  unsigned short* w2t = (unsigned short*)(ws + 75677952);
  unsigned short* hbuf = (unsigned short*)(ws + 109232384);
  float* ybuf = (float*)(ws + 142786816);

  // router (also converts hs -> bf16), then list construction
  router_kernel<<<256, 64, 0, stream>>>(hs, rk, wout, tw, choice, hsb);
  build_lists<<<1, 1024, 0, stream>>>(choice, counts, list);

  // weight conversions
  cvt_bf16<<<4096, 256, 0, stream>>>(w1, w1b, (int)(EFD / 4));
  cvt_bf16<<<4096, 256, 0, stream>>>(v1, v1b, (int)(EFD / 4));
  transpose_w2<<<dim3(ND / 32, NF / 32, NE), dim3(32, 8), 0, stream>>>(w2, w2t);

  // fused pass1+2: h = silu(X@w1^T) * (X@v1^T)  (BM=256, 512 thr)
  // grid = 8e x 16mt x 16nt = 2048
  gemm_fused<<<2048, 512, 0, stream>>>(counts, list, hsb, w1b, v1b, hbuf);

  // pass3: y = h @ w2t^T  (BM=256, BN=256, split-K=2)
  // grid = 8e x 16mt x (4nt x 2kh) = 1024
  gemm_p3<<<1024, 512, 0, stream>>>(counts, list, hbuf, w2t, ybuf);

  combine_kernel<<<2048, 256, 0, stream>>>(ybuf, tw, out);
}

// Round 10
// 286.917 us; speedup vs baseline: 1.1996x; 1.1996x over previous
//
#include <hip/hip_runtime.h>
#include <stdint.h>
#include <math.h>

// Problem constants (DBRX FFN): B=2 S=2048 D=1024 E=8 F=2048 K=2
#define NB 2
#define NS 2048
#define ND 1024
#define NE 8
#define NF 2048
#define NTOK (NB*NS)          // 4096 tokens
#define EFD ((size_t)NE*NF*ND)

typedef short bf16x8 __attribute__((ext_vector_type(8)));
typedef float f32x4 __attribute__((ext_vector_type(4)));

__device__ __forceinline__ unsigned short f2bf(float f) {
  unsigned u = __float_as_uint(f);
  unsigned r = (u + 0x7FFFu + ((u >> 16) & 1u)) >> 16;
  return (unsigned short)r;
}

__device__ __forceinline__ void async16(unsigned short* lds, const unsigned short* g) {
  __builtin_amdgcn_global_load_lds(
      (const __attribute__((address_space(1))) unsigned int*)g,
      (__attribute__((address_space(3))) unsigned int*)lds, 16, 0, 0);
}

#define VMCNT(n) asm volatile("s_waitcnt vmcnt(" #n ")" ::: "memory")
#define LGKM0    asm volatile("s_waitcnt lgkmcnt(0)" ::: "memory")
#define SBAR     __builtin_amdgcn_s_barrier()
#define SCHED0   __builtin_amdgcn_sched_barrier(0)

// ---------------- convert fp32 -> bf16 (vectorized) ----------------
__global__ void cvt_bf16(const float* __restrict__ src,
                         unsigned short* __restrict__ dst, int n4) {
  int i = blockIdx.x * blockDim.x + threadIdx.x;
  int stride = gridDim.x * blockDim.x;
  for (; i < n4; i += stride) {
    float4 v = ((const float4*)src)[i];
    ushort4 o;
    o.x = f2bf(v.x); o.y = f2bf(v.y); o.z = f2bf(v.z); o.w = f2bf(v.w);
    ((ushort4*)dst)[i] = o;
  }
}

// ---------------- transpose w2 (E,F,D) fp32 -> w2t (E,D,F) bf16 ----------------
__global__ void transpose_w2(const float* __restrict__ w2,
                             unsigned short* __restrict__ w2t) {
  __shared__ float tile[32][33];
  int e = blockIdx.z;
  int d0 = blockIdx.x * 32, f0 = blockIdx.y * 32;
  int tx = threadIdx.x, ty = threadIdx.y;
  const float* src = w2 + (size_t)e * NF * ND;
  unsigned short* dst = w2t + (size_t)e * ND * NF;
#pragma unroll
  for (int i = ty; i < 32; i += 8)
    tile[i][tx] = src[(size_t)(f0 + i) * ND + d0 + tx];
  __syncthreads();
#pragma unroll
  for (int i = ty; i < 32; i += 8)
    dst[(size_t)(d0 + i) * NF + f0 + tx] = f2bf(tile[tx][i]);
}

// ---------------- router: wave per 16 tokens, 4 lanes per token ----------------
__global__ void router_kernel(const float* __restrict__ hs,
                              const float* __restrict__ rk,
                              float* __restrict__ wout,   // [NTOK][NE]
                              float* __restrict__ tw,     // [NTOK][2]
                              int* __restrict__ choice,   // [NTOK] e0 | e1<<4
                              unsigned short* __restrict__ hsb) {
  int lane = threadIdx.x;            // 64
  int tt = lane & 15, part = lane >> 4;
  int t = blockIdx.x * 16 + tt;      // 256 blocks
  const float4* hrow = (const float4*)(hs + (size_t)t * ND) + part * 64;
  ushort4* hb4 = (ushort4*)(hsb + (size_t)t * ND) + part * 64;
  const float4* rk4 = (const float4*)rk + part * 512;
  float acc[NE];
#pragma unroll
  for (int e = 0; e < NE; ++e) acc[e] = 0.f;
#pragma unroll 4
  for (int i = 0; i < 64; ++i) {
    float4 x = hrow[i];
    ushort4 o;
    o.x = f2bf(x.x); o.y = f2bf(x.y); o.z = f2bf(x.z); o.w = f2bf(x.w);
    hb4[i] = o;
    float xs[4] = {x.x, x.y, x.z, x.w};
#pragma unroll
    for (int j = 0; j < 4; ++j) {
      float4 r0 = rk4[i * 8 + j * 2];
      float4 r1 = rk4[i * 8 + j * 2 + 1];
      acc[0] += xs[j] * r0.x; acc[1] += xs[j] * r0.y;
      acc[2] += xs[j] * r0.z; acc[3] += xs[j] * r0.w;
      acc[4] += xs[j] * r1.x; acc[5] += xs[j] * r1.y;
      acc[6] += xs[j] * r1.z; acc[7] += xs[j] * r1.w;
    }
  }
#pragma unroll
  for (int e = 0; e < NE; ++e) {
    acc[e] += __shfl_xor(acc[e], 16, 64);
    acc[e] += __shfl_xor(acc[e], 32, 64);
  }
  if (part == 0) {
    float mx = acc[0]; int i0 = 0;
#pragma unroll
    for (int e = 1; e < NE; ++e) if (acc[e] > mx) { mx = acc[e]; i0 = e; }
    float m2 = -3.4e38f; int i1 = 0;
#pragma unroll
    for (int e = 0; e < NE; ++e) if (e != i0 && acc[e] > m2) { m2 = acc[e]; i1 = e; }
    float p[NE]; float den = 0.f;
#pragma unroll
    for (int e = 0; e < NE; ++e) { p[e] = expf(acc[e] - mx); den += p[e]; }
    float inv = 1.f / den;
#pragma unroll
    for (int e = 0; e < NE; ++e) { p[e] *= inv; wout[t * NE + e] = p[e]; }
    float w0 = p[i0], w1 = p[i1];
    float s = 1.f / (w0 + w1);
    tw[t * 2 + 0] = w0 * s;
    tw[t * 2 + 1] = w1 * s;
    choice[t] = i0 | (i1 << 4);
  }
}

// ---------------- build per-expert token lists (single block, LDS atomics) ----
__global__ void build_lists(const int* __restrict__ choice,
                            int* __restrict__ counts,
                            int* __restrict__ list) {
  __shared__ int lcnt[NE];
  int tid = threadIdx.x;  // 1024
  if (tid < NE) lcnt[tid] = 0;
  __syncthreads();
  int4 c4 = ((const int4*)choice)[tid];
  int cs[4] = {c4.x, c4.y, c4.z, c4.w};
#pragma unroll
  for (int j = 0; j < 4; ++j) {
    int t = tid * 4 + j;
    int e0 = cs[j] & 15, e1 = (cs[j] >> 4) & 15;
    int p0 = atomicAdd(&lcnt[e0], 1);
    list[e0 * NTOK + p0] = t << 1;
    int p1 = atomicAdd(&lcnt[e1], 1);
    list[e1 * NTOK + p1] = (t << 1) | 1;
  }
  __syncthreads();
  if (tid < NE) counts[tid] = lcnt[tid];
}

// ============ fused pass1+2: R8 structure + XCD panel-group mapping ==========
// 256 thr = 4 waves (2x2). BM=128, BN=128 per matrix (w1,v1), BK=32.
// Ring-3 24KB LDS bufs (2 blocks/CU), stage-ahead-2, VMCNT(12/6/0),
// chunk-XOR swizzle slot^((row>>1)&3), 32 MFMA/kt/wave (acc1+acc2 4x4).
// XCD mapping (bid%8 -> XCD round-robin): group g=(e,nt) pinned to XCD nt&7;
// all mt-blocks of a group co-resident on one XCD -> 512KB B-panel L2-local.
// Balance: per XCD per expert exactly 2 nt-panels (nt&7 uniform) -- expert
// count skew affects all XCDs equally.
__global__ __launch_bounds__(256, 2) void gemm_fused(
    const int* __restrict__ counts, const int* __restrict__ list,
    const unsigned short* __restrict__ A,    // hsb [NTOK][ND]
    const unsigned short* __restrict__ B1,   // w1b [E][F][D]
    const unsigned short* __restrict__ B2,   // v1b
    unsigned short* __restrict__ H) {        // hbuf [2*NTOK][NF]
  int p = blockIdx.x;               // grid 4096
  int xcd = p & 7, slot = p >> 3;   // slot 0..511
  int gg = slot >> 5, mt = slot & 31;
  int g = gg * 8 + xcd;             // g = e*16 + nt  (g&7 == nt&7 == xcd)
  int e = g >> 4, nt = g & 15;
  int cnt = counts[e];
  if (mt * 128 >= cnt) return;

  __shared__ unsigned short lds[3][12288];   // 3 x 24KB

  int tid = threadIdx.x;
  int wid = tid >> 6, lane = tid & 63;
  int wr = wid >> 1, wc = wid & 1;
  int l15 = lane & 15, l4 = lane >> 4;
  const int* mylist = list + e * NTOK;

  int trow = tid >> 2;
  int co = ((tid & 3) ^ ((tid >> 3) & 3)) * 8;
  const unsigned short* aS0;
  const unsigned short* aS1;
  {
    int r0 = mt * 128 + trow;
    int r1 = r0 + 64;
    if (r0 >= cnt) r0 = cnt - 1;
    if (r1 >= cnt) r1 = cnt - 1;
    int e0 = mylist[r0], e1 = mylist[r1];
    aS0 = A + (size_t)(e0 >> 1) * ND + co;
    aS1 = A + (size_t)(e1 >> 1) * ND + co;
  }
  const unsigned short* b1S0 = B1 + (size_t)e * NF * ND + (size_t)(nt * 128 + trow) * ND + co;
  const unsigned short* b1S1 = b1S0 + (size_t)64 * ND;
  const unsigned short* b2S0 = B2 + (size_t)e * NF * ND + (size_t)(nt * 128 + trow) * ND + co;
  const unsigned short* b2S1 = b2S0 + (size_t)64 * ND;

  int rowA[4], rowB[4];
#pragma unroll
  for (int mi = 0; mi < 4; ++mi) {
    int r = wr * 64 + mi * 16 + l15;
    rowA[mi] = r * 64 + ((l4 ^ ((r >> 1) & 3)) << 4);
  }
#pragma unroll
  for (int ni = 0; ni < 4; ++ni) {
    int r = wc * 64 + ni * 16 + l15;
    rowB[ni] = r * 64 + ((l4 ^ ((r >> 1) & 3)) << 4);
  }

  f32x4 acc1[4][4], acc2[4][4];
#pragma unroll
  for (int mi = 0; mi < 4; ++mi)
#pragma unroll
    for (int ni = 0; ni < 4; ++ni) {
      f32x4 z = {0.f, 0.f, 0.f, 0.f};
      acc1[mi][ni] = z; acc2[mi][ni] = z;
    }

  auto STAGE = [&](int c, int kt) {
    int ko = kt * 32;
    unsigned short* base = &lds[c][0] + tid * 8;
    async16(base,         aS0 + ko);
    async16(base + 2048,  aS1 + ko);
    async16(base + 4096,  b1S0 + ko);
    async16(base + 6144,  b1S1 + ko);
    async16(base + 8192,  b2S0 + ko);
    async16(base + 10240, b2S1 + ko);
  };

  const int kT = ND / 32;  // 32
  STAGE(0, 0); STAGE(1, 1); STAGE(2, 2);

  int cur = 0;
  for (int kt = 0; kt < kT; ++kt) {
    if (kt + 2 < kT)      { VMCNT(12); }
    else if (kt + 1 < kT) { VMCNT(6); }
    else                  { VMCNT(0); }
    SCHED0;
    SBAR;

    const char* la = (const char*)&lds[cur][0];
    const char* lb1 = la + 8192;
    const char* lb2 = la + 16384;
    bf16x8 a[4], b1[4], b2[4];
#pragma unroll
    for (int mi = 0; mi < 4; ++mi)
      a[mi] = *(const bf16x8*)(la + rowA[mi]);
#pragma unroll
    for (int ni = 0; ni < 4; ++ni) {
      b1[ni] = *(const bf16x8*)(lb1 + rowB[ni]);
      b2[ni] = *(const bf16x8*)(lb2 + rowB[ni]);
    }
    LGKM0;
    SCHED0;
    SBAR;
    if (kt + 3 < kT) STAGE(cur, kt + 3);

    __builtin_amdgcn_s_setprio(1);
#pragma unroll
    for (int mi = 0; mi < 4; ++mi)
#pragma unroll
      for (int ni = 0; ni < 4; ++ni) {
        acc1[mi][ni] = __builtin_amdgcn_mfma_f32_16x16x32_bf16(
            a[mi], b1[ni], acc1[mi][ni], 0, 0, 0);
        acc2[mi][ni] = __builtin_amdgcn_mfma_f32_16x16x32_bf16(
            a[mi], b2[ni], acc2[mi][ni], 0, 0, 0);
      }
    __builtin_amdgcn_s_setprio(0);

    cur = (cur == 2) ? 0 : cur + 1;
  }

  int rowbase = mt * 128 + wr * 64;
  int colbase = nt * 128 + wc * 64;
#pragma unroll
  for (int mi = 0; mi < 4; ++mi) {
#pragma unroll
    for (int j = 0; j < 4; ++j) {
      int r = rowbase + mi * 16 + l4 * 4 + j;
      if (r >= cnt) continue;
      int entry = mylist[r];
      long crow = (long)(entry & 1) * NTOK + (entry >> 1);
#pragma unroll
      for (int ni = 0; ni < 4; ++ni) {
        int c = colbase + ni * 16 + l15;
        float x1 = acc1[mi][ni][j];
        float x2 = acc2[mi][ni][j];
        float h = (x1 / (1.f + expf(-x1))) * x2;
        H[crow * (long)NF + c] = f2bf(h);
      }
    }
  }
}

// ============ pass3: y = h @ w2t^T, BN=256, split-K=2, XCD mapping ===========
// 256 thr = 4 waves. A-tile 128 gathered rows, B-tile 256 w2t D-rows, BK=32.
// acc[4][8], 32 MFMA/kt. Ring-3 24KB bufs, VMCNT(12/6/0), same swizzle.
// XCD mapping: group (e,nt,kh) pinned to XCD (nt*2+kh)&7 -- exactly covers
// all 8 XCDs per expert; 512KB w2t panel (per kh half) L2-local.
__global__ __launch_bounds__(256, 2) void gemm_p3(
    const int* __restrict__ counts, const int* __restrict__ list,
    const unsigned short* __restrict__ Ah,   // hbuf [2*NTOK][NF]
    const unsigned short* __restrict__ Bw,   // w2t [E][ND][NF]
    float* __restrict__ Y) {                 // [2 kh][2*NTOK][ND] fp32
  int p = blockIdx.x;               // grid 2048
  int xcd = p & 7, slot = p >> 3;   // slot 0..255
  int e = slot >> 5, mt = slot & 31;
  int nt = xcd >> 1, kh = xcd & 1;
  int cnt = counts[e];
  if (mt * 128 >= cnt) return;

  __shared__ unsigned short lds[3][12288];   // 3 x 24KB (A 8KB + B 16KB)

  int tid = threadIdx.x;
  int wid = tid >> 6, lane = tid & 63;
  int wr = wid >> 1, wc = wid & 1;
  int l15 = lane & 15, l4 = lane >> 4;
  const int* mylist = list + e * NTOK;

  int trow = tid >> 2;
  int co = ((tid & 3) ^ ((tid >> 3) & 3)) * 8;
  const unsigned short* aS[2];
#pragma unroll
  for (int g = 0; g < 2; ++g) {
    int r = mt * 128 + g * 64 + trow;
    if (r >= cnt) r = cnt - 1;
    int entry = mylist[r];
    long crow = (long)(entry & 1) * NTOK + (entry >> 1);
    aS[g] = Ah + crow * (long)NF + kh * 1024 + co;
  }
  const unsigned short* bS[4];
#pragma unroll
  for (int g = 0; g < 4; ++g) {
    int d = nt * 256 + g * 64 + trow;
    bS[g] = Bw + (size_t)e * ND * NF + (size_t)d * NF + kh * 1024 + co;
  }

  int rowA[4], rowB[8];
#pragma unroll
  for (int mi = 0; mi < 4; ++mi) {
    int r = wr * 64 + mi * 16 + l15;
    rowA[mi] = r * 64 + ((l4 ^ ((r >> 1) & 3)) << 4);
  }
#pragma unroll
  for (int ni = 0; ni < 8; ++ni) {
    int r = wc * 128 + ni * 16 + l15;
    rowB[ni] = 8192 + r * 64 + ((l4 ^ ((r >> 1) & 3)) << 4);
  }

  f32x4 acc[4][8];
#pragma unroll
  for (int mi = 0; mi < 4; ++mi)
#pragma unroll
    for (int ni = 0; ni < 8; ++ni) {
      f32x4 z = {0.f, 0.f, 0.f, 0.f};
      acc[mi][ni] = z;
    }

  auto STAGE = [&](int c, int kt) {
    int ko = kt * 32;
    unsigned short* base = &lds[c][0] + tid * 8;
    async16(base,         aS[0] + ko);
    async16(base + 2048,  aS[1] + ko);
    async16(base + 4096,  bS[0] + ko);
    async16(base + 6144,  bS[1] + ko);
    async16(base + 8192,  bS[2] + ko);
    async16(base + 10240, bS[3] + ko);
  };

  const int kT = 32;   // 1024 (per kh) / 32
  STAGE(0, 0); STAGE(1, 1); STAGE(2, 2);

  int cur = 0;
  for (int kt = 0; kt < kT; ++kt) {
    if (kt + 2 < kT)      { VMCNT(12); }
    else if (kt + 1 < kT) { VMCNT(6); }
    else                  { VMCNT(0); }
    SCHED0;
    SBAR;

    const char* buf = (const char*)&lds[cur][0];
    bf16x8 a[4], b[8];
#pragma unroll
    for (int mi = 0; mi < 4; ++mi)
      a[mi] = *(const bf16x8*)(buf + rowA[mi]);
#pragma unroll
    for (int ni = 0; ni < 8; ++ni)
      b[ni] = *(const bf16x8*)(buf + rowB[ni]);
    LGKM0;
    SCHED0;
    SBAR;
    if (kt + 3 < kT) STAGE(cur, kt + 3);

    __builtin_amdgcn_s_setprio(1);
#pragma unroll
    for (int mi = 0; mi < 4; ++mi)
#pragma unroll
      for (int ni = 0; ni < 8; ++ni)
        acc[mi][ni] = __builtin_amdgcn_mfma_f32_16x16x32_bf16(
            a[mi], b[ni], acc[mi][ni], 0, 0, 0);
    __builtin_amdgcn_s_setprio(0);

    cur = (cur == 2) ? 0 : cur + 1;
  }

  float* Yp = Y + (size_t)kh * 2 * NTOK * ND;
#pragma unroll
  for (int mi = 0; mi < 4; ++mi)
#pragma unroll
    for (int j = 0; j < 4; ++j) {
      int r = mt * 128 + wr * 64 + mi * 16 + l4 * 4 + j;
      if (r >= cnt) continue;
      int entry = mylist[r];
      long crow = (long)(entry & 1) * NTOK + (entry >> 1);
#pragma unroll
      for (int ni = 0; ni < 8; ++ni) {
        int d = nt * 256 + wc * 128 + ni * 16 + l15;
        Yp[crow * (long)ND + d] = acc[mi][ni][j];
      }
    }
}

// ---------------- combine: out = tw0*(y0a+y0b) + tw1*(y1a+y1b) --------------
__global__ void combine_kernel(const float* __restrict__ ybuf,
                               const float* __restrict__ tw,
                               float* __restrict__ out) {
  const int S4 = NTOK * ND / 4;        // slot stride (float4)
  const int KH4 = 2 * NTOK * ND / 4;   // kh stride (float4)
  int i = blockIdx.x * blockDim.x + threadIdx.x;
  int stride = gridDim.x * blockDim.x;
  const float4* yb = (const float4*)ybuf;
  for (; i < S4; i += stride) {
    int t = i >> 8;
    float w0 = tw[t * 2], w1 = tw[t * 2 + 1];
    float4 a0 = yb[i], b0 = yb[i + KH4];
    float4 a1 = yb[i + S4], b1 = yb[i + S4 + KH4];
    float4 o;
    o.x = w0 * (a0.x + b0.x) + w1 * (a1.x + b1.x);
    o.y = w0 * (a0.y + b0.y) + w1 * (a1.y + b1.y);
    o.z = w0 * (a0.z + b0.z) + w1 * (a1.z + b1.z);
    o.w = w0 * (a0.w + b0.w) + w1 * (a1.w + b1.w);
    ((float4*)out)[i] = o;
  }
}

// ---------------- workspace layout (bytes) ----------------
// counts:   0         (256)
// list:     256       (131072)     end 131328
// tw:       131328    (32768)      end 164096
// choice:   164096    (16384)      end 180480
// hsb:      180480    (8388608)    end 8569088
// w1b:      8569088   (33554432)   end 42123520
// v1b:      42123520  (33554432)   end 75677952
// w2t:      75677952  (33554432)   end 109232384
// hbuf:     109232384 (33554432)   end 142786816
// ybuf:     142786816 (67108864)   end 209895680   [2 kh][2*NTOK][ND] fp32

extern "C" void kernel_launch(void* const* d_in, const int* in_sizes, int n_in,
                              void* d_out, int out_size, void* d_ws, size_t ws_size,
                              hipStream_t stream) {
  const float* hs = (const float*)d_in[0];
  const float* rk = (const float*)d_in[1];
  const float* w1 = (const float*)d_in[2];
  const float* v1 = (const float*)d_in[3];
  const float* w2 = (const float*)d_in[4];
  float* out = (float*)d_out;
  float* wout = out + (size_t)NTOK * ND;

  char* ws = (char*)d_ws;
  int* counts = (int*)(ws + 0);
  int* list = (int*)(ws + 256);
  float* tw = (float*)(ws + 131328);
  int* choice = (int*)(ws + 164096);
  unsigned short* hsb = (unsigned short*)(ws + 180480);
  unsigned short* w1b = (unsigned short*)(ws + 8569088);
  unsigned short* v1b = (unsigned short*)(ws + 42123520);
  unsigned short* w2t = (unsigned short*)(ws + 75677952);
  unsigned short* hbuf = (unsigned short*)(ws + 109232384);
  float* ybuf = (float*)(ws + 142786816);

  // router (also converts hs -> bf16), then list construction
  router_kernel<<<256, 64, 0, stream>>>(hs, rk, wout, tw, choice, hsb);
  build_lists<<<1, 1024, 0, stream>>>(choice, counts, list);

  // weight conversions
  cvt_bf16<<<4096, 256, 0, stream>>>(w1, w1b, (int)(EFD / 4));
  cvt_bf16<<<4096, 256, 0, stream>>>(v1, v1b, (int)(EFD / 4));
  transpose_w2<<<dim3(ND / 32, NF / 32, NE), dim3(32, 8), 0, stream>>>(w2, w2t);

  // fused pass1+2: h = silu(X@w1^T) * (X@v1^T)   (R8 structure + XCD map)
  // grid = 4096: xcd=bid&7, slot=bid>>3 -> g=(slot>>5)*8+xcd, mt=slot&31
  gemm_fused<<<4096, 256, 0, stream>>>(counts, list, hsb, w1b, v1b, hbuf);

  // pass3: y = h @ w2t^T, BN=256, split-K=2  (R8 structure + XCD map)
  // grid = 2048: xcd=bid&7 -> (nt,kh); slot=bid>>3 -> (e,mt)
  gemm_p3<<<2048, 256, 0, stream>>>(counts, list, hbuf, w2t, ybuf);

  combine_kernel<<<2048, 256, 0, stream>>>(ybuf, tw, out);
}